// Round 17
// baseline (446.794 us; speedup 1.0000x reference)
//
#include <hip/hip_runtime.h>

#define B_    4
#define T_    2048
#define C_    2048
#define H_    16
#define HD_   128
#define LDQK  4096   // qk buffer row stride (q | k)

typedef __attribute__((ext_vector_type(8))) short short8v;    // 8 bf16
typedef __attribute__((ext_vector_type(4))) float float4v;    // 16x16 C/D
typedef __attribute__((ext_vector_type(16))) float float16v;  // 32x32 C/D

typedef const __attribute__((address_space(1))) void* gld_src_t;
typedef __attribute__((address_space(3))) void* gld_dst_t;
#define GLDS16(g, l) __builtin_amdgcn_global_load_lds((gld_src_t)(g), (gld_dst_t)(l), 16, 0, 0)

__device__ __forceinline__ unsigned short f2bf(float f) {
  unsigned int u = __float_as_uint(f);
  u += 0x7fffu + ((u >> 16) & 1u);   // RNE
  return (unsigned short)(u >> 16);
}
__device__ __forceinline__ float bf2f(unsigned short s) {
  return __uint_as_float(((unsigned int)s) << 16);
}
// hardware packed f32x2 -> bf16x2 convert (RNE), T12
__device__ __forceinline__ unsigned int cvtpk_bf16(float lo, float hi) {
  unsigned int r;
  asm("v_cvt_pk_bf16_f32 %0, %1, %2" : "=v"(r) : "v"(lo), "v"(hi));
  return r;
}

// ---------------- fused f32 -> bf16 convert (x | Wq | Wk | Wv | Wp) ----------------
__global__ void cvt5_kernel(const float* __restrict__ x,
                            const float* __restrict__ wq, const float* __restrict__ wk,
                            const float* __restrict__ wv, const float* __restrict__ wp,
                            unsigned short* __restrict__ xbf, unsigned short* __restrict__ wdst) {
  int i = blockIdx.x * blockDim.x + threadIdx.x;   // float4 index
  const float4* s;
  ushort4* d;
  if (i < 4194304) {
    s = reinterpret_cast<const float4*>(x) + i;
    d = reinterpret_cast<ushort4*>(xbf) + i;
  } else {
    int j = i - 4194304;
    int w = j >> 20;
    const float* wsrc = (w == 0) ? wq : (w == 1) ? wk : (w == 2) ? wv : wp;
    s = reinterpret_cast<const float4*>(wsrc) + (j & 1048575);
    d = reinterpret_cast<ushort4*>(wdst) + j;     // Wq|Wk|Wv|Wp contiguous in ws
  }
  float4 v = *s;
  ushort4 o;
  o.x = f2bf(v.x); o.y = f2bf(v.y); o.z = f2bf(v.z); o.w = f2bf(v.w);
  *d = o;
}

// ---------------- 256x256 bf16 GEMM (round-14 structure: session best) ----------
// Register-pipelined quarters: read q+1's fragments BEFORE q's MFMA cluster
// (two A-sets + two B-sets) so ds_reads drain under MFMA; no setprio in loop.
// Whole tile t+1 prefetched at tile start into the dead buffer; one
// lgkmcnt(0)+sched_barrier+vmcnt(0)+s_barrier per K-tile. 128B LDS rows,
// (row&7)<<4 XOR swizzle (0 bank conflicts), inverse-permuted GLDS source.
// launch_bounds(512,2): VGPR cap 256 (round-11: (512,4) -> spill -> 6.5GB HBM).
// Round-15 lesson: B direct global->reg is a 16-line gather -> both operands LDS.
// MODE 0: f32 C row-major (out-proj).
// MODE 3: merged QKV -> bn<16: bf16 C + fused RoPE; bn>=16: V^T to vt[bh][d][t].

#define ISSUE_HALF(MAT, HA, KT, CBUF)                                             \
  { const unsigned short* gp_ = (MAT) ? Bm : A;                                   \
    const size_t gb_ = (MAT) ? bbase : abase;                                     \
    _Pragma("unroll")                                                             \
    for (int i_ = 0; i_ < 2; ++i_) {                                              \
      int fo_ = (i_ * 512 + tid) * 16;             /* 0..16383 */                 \
      int rl_ = fo_ >> 7;                          /* 0..127  */                  \
      int row_ = (HA) * 128 + rl_;                                                \
      int g_ = (fo_ >> 4) & 7;                                                    \
      int ce_ = ((g_ ^ (rl_ & 7)) << 3);           /* inverse swizzle on src */   \
      GLDS16(gp_ + gb_ + (size_t)row_ * K + (KT) * 64 + ce_,                      \
             lds + (CBUF) * 65536 + (MAT) * 32768 + (HA) * 16384 + fo_);          \
    } }

#define RD_A(dst, MI, KK, CBUF)                                                   \
  { int row_ = wm * 128 + (MI) * 16 + lr;                                         \
    dst = *reinterpret_cast<const short8v*>(                                      \
        lds + (CBUF) * 65536 + row_ * 128 + (((KK) * 64 + lg * 16) ^ ((row_ & 7) << 4))); }

#define RD_B(dst, NI, KK, CBUF)                                                   \
  { int row_ = wn * 64 + (NI) * 16 + lr;                                          \
    dst = *reinterpret_cast<const short8v*>(                                      \
        lds + (CBUF) * 65536 + 32768 + row_ * 128 + (((KK) * 64 + lg * 16) ^ ((row_ & 7) << 4))); }

#define MFMA16(MB, AV, BV)                                                        \
    _Pragma("unroll")                                                             \
    for (int ni_ = 0; ni_ < 4; ++ni_) {                                           \
      _Pragma("unroll")                                                           \
      for (int mi_ = 0; mi_ < 4; ++mi_)                                           \
        acc[(MB)+mi_][ni_] = __builtin_amdgcn_mfma_f32_16x16x32_bf16(AV[mi_], BV[ni_], acc[(MB)+mi_][ni_], 0,0,0); \
    }

template<int MODE>
__global__ __launch_bounds__(512, 2)
void gemm256(const unsigned short* __restrict__ A, const unsigned short* __restrict__ Bm,
             void* __restrict__ Cout, unsigned short* __restrict__ vtp,
             int K, int NB, int ldc,
             const float* __restrict__ rc, const float* __restrict__ rs)
{
  extern __shared__ char lds[];
  const int tid = threadIdx.x;
  const int l = tid & 63, w = tid >> 6;
  const int lr = l & 15, lg = l >> 4;
  const int wm = w >> 2, wn = w & 3;

  // XCD-bijective swizzle (m204)
  const int nwg = (int)gridDim.x;
  const int orig = (int)blockIdx.x;
  const int qq = nwg >> 3, rr = nwg & 7;
  const int xcd = orig & 7, idx = orig >> 3;
  const int wg = (xcd < rr ? xcd * (qq + 1) : rr * (qq + 1) + (xcd - rr) * qq) + idx;
  const int bm = wg / NB, bn = wg % NB;

  const size_t abase = (size_t)bm * 256 * (size_t)K;
  const size_t bbase = (size_t)bn * 256 * (size_t)K;

  float4v acc[8][4];
  const float4v fz = {0.f, 0.f, 0.f, 0.f};
#pragma unroll
  for (int i = 0; i < 8; ++i)
#pragma unroll
    for (int j = 0; j < 4; ++j) acc[i][j] = fz;

  const int nk = K >> 6;

  // prologue: tile0 -> buf0, then preload quarter-0 fragments
  ISSUE_HALF(1, 0, 0, 0)
  ISSUE_HALF(1, 1, 0, 0)
  ISSUE_HALF(0, 0, 0, 0)
  ISSUE_HALF(0, 1, 0, 0)
  asm volatile("s_waitcnt vmcnt(0)" ::: "memory");
  __builtin_amdgcn_s_barrier();

  short8v aC[4], aN[4], bC[4], bN[4];
  RD_A(aC[0], 0, 0, 0) RD_A(aC[1], 1, 0, 0) RD_A(aC[2], 2, 0, 0) RD_A(aC[3], 3, 0, 0)
  RD_B(bC[0], 0, 0, 0) RD_B(bC[1], 1, 0, 0) RD_B(bC[2], 2, 0, 0) RD_B(bC[3], 3, 0, 0)

  for (int t = 0; t < nk; ++t) {
    const int c = t & 1;

    // issue ALL of tile t+1 into the dead buffer at tile start (max distance)
    if (t + 1 < nk) {
      ISSUE_HALF(1, 0, t + 1, c ^ 1)
      ISSUE_HALF(1, 1, t + 1, c ^ 1)
      ISSUE_HALF(0, 0, t + 1, c ^ 1)
      ISSUE_HALF(0, 1, t + 1, c ^ 1)
    }

    // ---- pipelined quarters: read q+1 regs, then MFMA q (reads drain under MFMA)
    RD_A(aN[0], 4, 0, c) RD_A(aN[1], 5, 0, c) RD_A(aN[2], 6, 0, c) RD_A(aN[3], 7, 0, c)
    MFMA16(0, aC, bC)                               // q0: mi0-3, kk0

    RD_A(aC[0], 0, 1, c) RD_A(aC[1], 1, 1, c) RD_A(aC[2], 2, 1, c) RD_A(aC[3], 3, 1, c)
    RD_B(bN[0], 0, 1, c) RD_B(bN[1], 1, 1, c) RD_B(bN[2], 2, 1, c) RD_B(bN[3], 3, 1, c)
    MFMA16(4, aN, bC)                               // q1: mi4-7, kk0

    RD_A(aN[0], 4, 1, c) RD_A(aN[1], 5, 1, c) RD_A(aN[2], 6, 1, c) RD_A(aN[3], 7, 1, c)
    MFMA16(0, aC, bN)                               // q2: mi0-3, kk1

    // tile boundary: our ds_reads of buf c done (so t+1's DMA can't corrupt),
    // t+1's staging landed (issued one full tile ago), all waves synced.
    asm volatile("s_waitcnt lgkmcnt(0)" ::: "memory");
    __builtin_amdgcn_sched_barrier(0);
    asm volatile("s_waitcnt vmcnt(0)" ::: "memory");
    __builtin_amdgcn_s_barrier();

    MFMA16(4, aN, bN)                               // q3: mi4-7, kk1

    if (t + 1 < nk) {
      RD_A(aC[0], 0, 0, c ^ 1) RD_A(aC[1], 1, 0, c ^ 1) RD_A(aC[2], 2, 0, c ^ 1) RD_A(aC[3], 3, 0, c ^ 1)
      RD_B(bC[0], 0, 0, c ^ 1) RD_B(bC[1], 1, 0, c ^ 1) RD_B(bC[2], 2, 0, c ^ 1) RD_B(bC[3], 3, 0, c ^ 1)
    }
  }

  // ---- epilogue
  const int row0 = bm * 256 + wm * 128;
  const int col0 = bn * 256 + wn * 64;
  if (MODE == 3 && bn >= 16) {
    // V projection -> vt[bh][d][t] (transposed, ushort4 packed)
#pragma unroll
    for (int mi = 0; mi < 8; ++mi)
#pragma unroll
      for (int ni = 0; ni < 4; ++ni) {
        int vcol = col0 - 4096 + ni * 16 + lr;   // 0..2047 -> h,d
        int hh = vcol >> 7, dd = vcol & 127;
        int row = row0 + mi * 16 + lg * 4;
        int bb = row >> 11, t0 = row & 2047;
        ushort4 o4;
        o4.x = f2bf(acc[mi][ni][0]); o4.y = f2bf(acc[mi][ni][1]);
        o4.z = f2bf(acc[mi][ni][2]); o4.w = f2bf(acc[mi][ni][3]);
        *reinterpret_cast<ushort4*>(vtp + (((size_t)(bb * 16 + hh)) << 18) + (((size_t)dd) << 11) + t0) = o4;
      }
  } else if (MODE == 3) {
    // Q|K projection + fused RoPE: pair (2i,2i+1) in adjacent lanes of C-frag.
    const float sgn = (lr & 1) ? 1.0f : -1.0f;
#pragma unroll
    for (int mi = 0; mi < 8; ++mi)
#pragma unroll
      for (int ni = 0; ni < 4; ++ni) {
        int col = col0 + ni * 16 + lr;
        int ii = (col & 127) >> 1;
#pragma unroll
        for (int r2 = 0; r2 < 4; ++r2) {
          int row = row0 + mi * 16 + lg * 4 + r2;
          int tt = row & 2047;
          float v = acc[mi][ni][r2];
          float vp = __shfl_xor(v, 1);
          float cs = rc[tt * 64 + ii];
          float sn = rs[tt * 64 + ii];
          float o = v * cs + sgn * vp * sn;
          ((unsigned short*)Cout)[(size_t)row * ldc + col] = f2bf(o);
        }
      }
  } else {
#pragma unroll
    for (int mi = 0; mi < 8; ++mi)
#pragma unroll
      for (int ni = 0; ni < 4; ++ni)
#pragma unroll
        for (int r2 = 0; r2 < 4; ++r2) {
          int row = row0 + mi * 16 + lg * 4 + r2;
          int col = col0 + ni * 16 + lr;
          ((float*)Cout)[(size_t)row * ldc + col] = acc[mi][ni][r2];
        }
  }
}

// ---------------- causal flash attention: merged 512-thread blocks ----------------
// 8 waves share ONE staged K/V stream: waves 0-3 compute heavy q-tile (15-bx),
// waves 4-7 light q-tile (bx) concurrently. Round-16 bug: co-resident blocks
// (wg, wg+256) got the SAME bx -> CUs with 64 vs 36 stages (imbalance).
// Fix: bx = (wg>>8)&1 ? 7-bx0 : bx0 -> co-resident pair is (bx, 7-bx) ->
// every CU carries exactly 50 stages. XCD colocation unchanged (bh keys wg&7).
__global__ __launch_bounds__(512, 2)
void attn_kernel(const unsigned short* __restrict__ qk,
                 const unsigned short* __restrict__ vt,
                 unsigned short* __restrict__ out)
{
  __shared__ unsigned short Kl[2][64 * 128];
  __shared__ unsigned short Vl[2][128 * 64];

  const int wg = (int)blockIdx.x;
  const int bh = ((wg >> 6) << 3) | (wg & 7);
  const int bx0 = (wg >> 3) & 7;
  const int bx = ((wg >> 8) & 1) ? (7 - bx0) : bx0;   // complementary across co-resident halves
  const int b = bh >> 4, h = bh & 15;
  const int tid = threadIdx.x, w = tid >> 6, l = tid & 63;
  const int q32 = l & 31, hi = l >> 5;
  const size_t rowbase = (size_t)b * T_;
  const unsigned short* kbase = qk + rowbase * LDQK + 2048 + h * HD_;
  const unsigned short* vbase = vt + (size_t)bh * (HD_ * (size_t)T_);
  const float SC = 0.12754089f;  // log2e / sqrt(128)
  const float16v z16 = {0.f,0.f,0.f,0.f,0.f,0.f,0.f,0.f,0.f,0.f,0.f,0.f,0.f,0.f,0.f,0.f};

  // wave -> q-tile: waves 0-3 heavy (qt=15-bx), waves 4-7 light (qt=bx)
  const int qt = (w >> 2) ? bx : (15 - bx);
  const int q0w = qt * 128 + (w & 3) * 32;
  const int qg = q0w + q32;
  const int nkv = 2 * (16 - bx);          // heavy tile count (covers light too)

#define STAGE(kv0_, bi_)                                                          \
  {                                                                               \
    _Pragma("unroll")                                                             \
    for (int i_ = 0; i_ < 2; ++i_) {                                              \
      int fo = (i_ * 512 + tid) * 16;                                             \
      int row = fo >> 8;                                                          \
      int cb = (fo & 255) ^ ((row & 15) << 4);                                    \
      GLDS16(kbase + (size_t)((kv0_) + row) * LDQK + (cb >> 1), (char*)Kl[bi_] + fo); \
    }                                                                             \
    _Pragma("unroll")                                                             \
    for (int i_ = 0; i_ < 2; ++i_) {                                              \
      int fo = (i_ * 512 + tid) * 16;                                             \
      int r6 = (fo >> 8) & 63;                                                    \
      int s_ = (fo >> 7) & 1;                                                     \
      int dd = r6 | ((s_ ^ ((r6 >> 3) & 1)) << 6);                                \
      int k16 = ((fo >> 4) & 7) ^ (dd & 7);                                       \
      GLDS16(vbase + (size_t)dd * T_ + (kv0_) + k16 * 8, (char*)Vl[bi_] + fo);    \
    }                                                                             \
  }

  // Q fragments (B-operand: col q=l&31, k=kf*16+hi*8+e), pre-scaled
  short8v qf[8];
#pragma unroll
  for (int kf = 0; kf < 8; ++kf) {
    short8v t = *reinterpret_cast<const short8v*>(
        qk + (rowbase + q0w + q32) * (size_t)LDQK + h * HD_ + kf * 16 + hi * 8);
    short8v r;
#pragma unroll
    for (int e = 0; e < 8; ++e) r[e] = (short)f2bf(bf2f((unsigned short)t[e]) * SC);
    qf[kf] = r;
  }

  float16v o[4];
#pragma unroll
  for (int db = 0; db < 4; ++db) o[db] = z16;
  float m_run = -1e30f, lsum = 0.f;

  STAGE(0, 0);
  __syncthreads();

  for (int tile = 0; tile < nkv; ++tile) {
    const int kv0 = tile * 64;
    const int bi = tile & 1;
    if (tile + 1 < nkv) STAGE((tile + 1) * 64, bi ^ 1);

    if (kv0 <= q0w + 31) {
      // ---- S^T = K Q^T : D[key][q], two 32-key blocks
      float16v stv[2];
      stv[0] = z16; stv[1] = z16;
      __builtin_amdgcn_s_setprio(1);
#pragma unroll
      for (int kb = 0; kb < 2; ++kb) {
        int key = kb * 32 + q32;
        int swz = (key & 15) << 4;
        int rbase = key * 256;
#pragma unroll
        for (int kf = 0; kf < 8; ++kf) {
          short8v ak = *reinterpret_cast<const short8v*>(
              (char*)Kl[bi] + rbase + ((kf * 32 + hi * 16) ^ swz));
          stv[kb] = __builtin_amdgcn_mfma_f32_32x32x16_bf16(ak, qf[kf], stv[kb], 0, 0, 0);
        }
      }
      __builtin_amdgcn_s_setprio(0);
      // ---- causal mask (only partial tiles)
      if (kv0 + 63 > q0w) {
#pragma unroll
        for (int kb = 0; kb < 2; ++kb)
#pragma unroll
          for (int r = 0; r < 16; ++r) {
            int key = kv0 + kb * 32 + (r & 3) + 8 * ((r >> 2) & 3) + 4 * hi;
            if (key > qg) stv[kb][r] = -1e30f;
          }
      }
      // ---- row max (in-register tree + 1 cross-half shfl)
      float t16[16];
#pragma unroll
      for (int r = 0; r < 16; ++r) t16[r] = fmaxf(stv[0][r], stv[1][r]);
#pragma unroll
      for (int s = 8; s >= 1; s >>= 1)
#pragma unroll
        for (int r = 0; r < s; ++r) t16[r] = fmaxf(t16[r], t16[r + s]);
      float pm = fmaxf(t16[0], __shfl_xor(t16[0], 32));

      // ---- deferred rescale (T13, THR=8)
      if (!__all(pm <= m_run + 8.0f)) {
        float mn = fmaxf(m_run, pm);
        float fac = exp2f(m_run - mn);
        lsum *= fac;
        m_run = mn;
#pragma unroll
        for (int r = 0; r < 16; ++r) {
          int src = (r & 3) + 8 * ((r >> 2) & 3) + 4 * hi;
          float fr = __shfl(fac, src);
#pragma unroll
          for (int db = 0; db < 4; ++db) o[db][r] *= fr;
        }
      }
      // ---- P = exp2(s - m), row sum
      {
        float s16[16];
#pragma unroll
        for (int r = 0; r < 16; ++r) {
          float p0 = exp2f(stv[0][r] - m_run);
          float p1 = exp2f(stv[1][r] - m_run);
          stv[0][r] = p0; stv[1][r] = p1;
          s16[r] = p0 + p1;
        }
#pragma unroll
        for (int s = 8; s >= 1; s >>= 1)
#pragma unroll
          for (int r = 0; r < s; ++r) s16[r] += s16[r + s];
        lsum += s16[0] + __shfl_xor(s16[0], 32);
      }
      // ---- pack P to bf16 words (HW cvt_pk), exchange halves, build A-frags
      unsigned int pw0[8], pw1[8], xw0[8], xw1[8];
#pragma unroll
      for (int j = 0; j < 8; ++j) {
        pw0[j] = cvtpk_bf16(stv[0][2 * j], stv[0][2 * j + 1]);
        pw1[j] = cvtpk_bf16(stv[1][2 * j], stv[1][2 * j + 1]);
      }
#pragma unroll
      for (int j = 0; j < 8; ++j) {
        xw0[j] = __shfl_xor(pw0[j], 32);
        xw1[j] = __shfl_xor(pw1[j], 32);
      }
      union UW { unsigned int u[4]; short8v v; };
      short8v pb[4];
      {
        UW a0, a1, c0, c1;
        a0.u[0] = hi ? xw0[2] : pw0[0];  a0.u[1] = hi ? xw0[3] : pw0[1];
        a0.u[2] = hi ? pw0[2] : xw0[0];  a0.u[3] = hi ? pw0[3] : xw0[1];
        a1.u[0] = hi ? xw0[6] : pw0[4];  a1.u[1] = hi ? xw0[7] : pw0[5];
        a1.u[2] = hi ? pw0[6] : xw0[4];  a1.u[3] = hi ? pw0[7] : xw0[5];
        c0.u[0] = hi ? xw1[2] : pw1[0];  c0.u[1] = hi ? xw1[3] : pw1[1];
        c0.u[2] = hi ? pw1[2] : xw1[0];  c0.u[3] = hi ? pw1[3] : xw1[1];
        c1.u[0] = hi ? xw1[6] : pw1[4];  c1.u[1] = hi ? xw1[7] : pw1[5];
        c1.u[2] = hi ? pw1[6] : xw1[4];  c1.u[3] = hi ? pw1[7] : xw1[5];
        pb[0] = a0.v; pb[1] = a1.v; pb[2] = c0.v; pb[3] = c1.v;
      }
      // ---- O += P V  (B-operand = packed V^T rows from swizzled Vl)
      __builtin_amdgcn_s_setprio(1);
#pragma unroll
      for (int db = 0; db < 4; ++db) {
        int dd = db * 32 + q32;
        int rb2 = (dd & 63) * 256 + ((((dd >> 6) ^ ((dd >> 3) & 1)) & 1) << 7);
        int swz = (dd & 7) << 4;
#pragma unroll
        for (int kb16 = 0; kb16 < 4; ++kb16) {
          short8v bv = *reinterpret_cast<const short8v*>(
              (char*)Vl[bi] + rb2 + ((kb16 * 32 + hi * 16) ^ swz));
          o[db] = __builtin_amdgcn_mfma_f32_32x32x16_bf16(pb[kb16], bv, o[db], 0, 0, 0);
        }
      }
      __builtin_amdgcn_s_setprio(0);
    }
    __syncthreads();
  }

  // ---- epilogue: normalize and store bf16
  float linv = 1.0f / lsum;
#pragma unroll
  for (int r = 0; r < 16; ++r) {
    int src = (r & 3) + 8 * ((r >> 2) & 3) + 4 * hi;
    float lr_ = __shfl(linv, src);
    size_t rowoff = (rowbase + q0w + src) * (size_t)C_ + h * HD_ + q32;
#pragma unroll
    for (int db = 0; db < 4; ++db)
      out[rowoff + db * 32] = f2bf(o[db][r] * lr_);
  }
#undef STAGE
}

// ---------------- launch ----------------
extern "C" void kernel_launch(void* const* d_in, const int* in_sizes, int n_in,
                              void* d_out, int out_size, void* d_ws, size_t ws_size,
                              hipStream_t stream) {
  (void)in_sizes; (void)n_in; (void)out_size; (void)ws_size;
  const float* x  = (const float*)d_in[0];
  const float* rc = (const float*)d_in[2];
  const float* rs = (const float*)d_in[3];
  const float* Wq = (const float*)d_in[4];
  const float* Wk = (const float*)d_in[5];
  const float* Wv = (const float*)d_in[6];
  const float* Wp = (const float*)d_in[7];
  float* outp = (float*)d_out;

  unsigned short* ws    = (unsigned short*)d_ws;
  unsigned short* x_bf  = ws;                       // 16,777,216
  unsigned short* wqkv  = x_bf + 16777216;          // 12,582,912 (Wq|Wk|Wv)
  unsigned short* wp_bf = wqkv + 12582912;          //  4,194,304 (contiguous after wqkv)
  unsigned short* qkbuf = wp_bf + 4194304;          // 33,554,432 (8192 x 4096)
  unsigned short* vtbuf = qkbuf + 33554432;         // 16,777,216 (64 x 128 x 2048)
  unsigned short* ao    = x_bf;                     // reuse after QKV GEMM

  // allow 128 KiB dynamic LDS (idempotent, capture-safe)
  hipFuncSetAttribute((const void*)gemm256<0>, hipFuncAttributeMaxDynamicSharedMemorySize, 131072);
  hipFuncSetAttribute((const void*)gemm256<3>, hipFuncAttributeMaxDynamicSharedMemorySize, 131072);

  // fused converts: x -> x_bf ; Wq|Wk|Wv|Wp -> wqkv..wp_bf (contiguous)
  cvt5_kernel<<<32768, 256, 0, stream>>>(x, Wq, Wk, Wv, Wp, x_bf, wqkv);

  // merged QKV projection: [8192,2048] x [6144,2048]^T, 768 blocks.
  // bn<16 -> q|k + fused RoPE into qkbuf; bn>=16 -> V transposed to vtbuf.
  gemm256<3><<<dim3(768), 512, 131072, stream>>>(x_bf, wqkv, qkbuf, vtbuf, 2048, 24, 4096, rc, rs);

  // merged-block causal attention (balanced: co-resident blocks get bx, 7-bx)
  attn_kernel<<<dim3(512), 512, 0, stream>>>(qkbuf, vtbuf, ao);

  // output projection -> f32
  gemm256<0><<<dim3(256), 512, 131072, stream>>>(ao, wp_bf, outp, nullptr, 2048, 8, 2048, nullptr, nullptr);
}

// Round 18
// 402.301 us; speedup vs baseline: 1.1106x; 1.1106x over previous
//
#include <hip/hip_runtime.h>

#define B_    4
#define T_    2048
#define C_    2048
#define H_    16
#define HD_   128
#define LDQK  4096   // qk buffer row stride (q | k)

typedef __attribute__((ext_vector_type(8))) short short8v;    // 8 bf16
typedef __attribute__((ext_vector_type(4))) float float4v;    // 16x16 C/D
typedef __attribute__((ext_vector_type(16))) float float16v;  // 32x32 C/D

typedef const __attribute__((address_space(1))) void* gld_src_t;
typedef __attribute__((address_space(3))) void* gld_dst_t;
#define GLDS16(g, l) __builtin_amdgcn_global_load_lds((gld_src_t)(g), (gld_dst_t)(l), 16, 0, 0)

__device__ __forceinline__ unsigned short f2bf(float f) {
  unsigned int u = __float_as_uint(f);
  u += 0x7fffu + ((u >> 16) & 1u);   // RNE
  return (unsigned short)(u >> 16);
}
__device__ __forceinline__ float bf2f(unsigned short s) {
  return __uint_as_float(((unsigned int)s) << 16);
}
// hardware packed f32x2 -> bf16x2 convert (RNE), T12
__device__ __forceinline__ unsigned int cvtpk_bf16(float lo, float hi) {
  unsigned int r;
  asm("v_cvt_pk_bf16_f32 %0, %1, %2" : "=v"(r) : "v"(lo), "v"(hi));
  return r;
}

// ---------------- fused f32 -> bf16 convert (x | Wq | Wk | Wv | Wp) ----------------
__global__ void cvt5_kernel(const float* __restrict__ x,
                            const float* __restrict__ wq, const float* __restrict__ wk,
                            const float* __restrict__ wv, const float* __restrict__ wp,
                            unsigned short* __restrict__ xbf, unsigned short* __restrict__ wdst) {
  int i = blockIdx.x * blockDim.x + threadIdx.x;   // float4 index
  const float4* s;
  ushort4* d;
  if (i < 4194304) {
    s = reinterpret_cast<const float4*>(x) + i;
    d = reinterpret_cast<ushort4*>(xbf) + i;
  } else {
    int j = i - 4194304;
    int w = j >> 20;
    const float* wsrc = (w == 0) ? wq : (w == 1) ? wk : (w == 2) ? wv : wp;
    s = reinterpret_cast<const float4*>(wsrc) + (j & 1048575);
    d = reinterpret_cast<ushort4*>(wdst) + j;     // Wq|Wk|Wv|Wp contiguous in ws
  }
  float4 v = *s;
  ushort4 o;
  o.x = f2bf(v.x); o.y = f2bf(v.y); o.z = f2bf(v.z); o.w = f2bf(v.w);
  *d = o;
}

// ---------------- 256x256 bf16 GEMM (round-14 structure: session best) ----------
// Register-pipelined quarters: read q+1's fragments BEFORE q's MFMA cluster
// (two A-sets + two B-sets) so ds_reads drain under MFMA; no setprio in loop.
// Whole tile t+1 prefetched at tile start into the dead buffer; one
// lgkmcnt(0)+sched_barrier+vmcnt(0)+s_barrier per K-tile. 128B LDS rows,
// (row&7)<<4 XOR swizzle (0 bank conflicts), inverse-permuted GLDS source.
// launch_bounds(512,2): VGPR cap 256 (round-11: (512,4) -> spill -> 6.5GB HBM).
// Round-15 lesson: B direct global->reg is a 16-line gather -> both operands LDS.
// MODE 0: f32 C row-major (out-proj).
// MODE 3: merged QKV -> bn<16: bf16 C + fused RoPE; bn>=16: V^T to vt[bh][d][t].

#define ISSUE_HALF(MAT, HA, KT, CBUF)                                             \
  { const unsigned short* gp_ = (MAT) ? Bm : A;                                   \
    const size_t gb_ = (MAT) ? bbase : abase;                                     \
    _Pragma("unroll")                                                             \
    for (int i_ = 0; i_ < 2; ++i_) {                                              \
      int fo_ = (i_ * 512 + tid) * 16;             /* 0..16383 */                 \
      int rl_ = fo_ >> 7;                          /* 0..127  */                  \
      int row_ = (HA) * 128 + rl_;                                                \
      int g_ = (fo_ >> 4) & 7;                                                    \
      int ce_ = ((g_ ^ (rl_ & 7)) << 3);           /* inverse swizzle on src */   \
      GLDS16(gp_ + gb_ + (size_t)row_ * K + (KT) * 64 + ce_,                      \
             lds + (CBUF) * 65536 + (MAT) * 32768 + (HA) * 16384 + fo_);          \
    } }

#define RD_A(dst, MI, KK, CBUF)                                                   \
  { int row_ = wm * 128 + (MI) * 16 + lr;                                         \
    dst = *reinterpret_cast<const short8v*>(                                      \
        lds + (CBUF) * 65536 + row_ * 128 + (((KK) * 64 + lg * 16) ^ ((row_ & 7) << 4))); }

#define RD_B(dst, NI, KK, CBUF)                                                   \
  { int row_ = wn * 64 + (NI) * 16 + lr;                                          \
    dst = *reinterpret_cast<const short8v*>(                                      \
        lds + (CBUF) * 65536 + 32768 + row_ * 128 + (((KK) * 64 + lg * 16) ^ ((row_ & 7) << 4))); }

#define MFMA16(MB, AV, BV)                                                        \
    _Pragma("unroll")                                                             \
    for (int ni_ = 0; ni_ < 4; ++ni_) {                                           \
      _Pragma("unroll")                                                           \
      for (int mi_ = 0; mi_ < 4; ++mi_)                                           \
        acc[(MB)+mi_][ni_] = __builtin_amdgcn_mfma_f32_16x16x32_bf16(AV[mi_], BV[ni_], acc[(MB)+mi_][ni_], 0,0,0); \
    }

template<int MODE>
__global__ __launch_bounds__(512, 2)
void gemm256(const unsigned short* __restrict__ A, const unsigned short* __restrict__ Bm,
             void* __restrict__ Cout, unsigned short* __restrict__ vtp,
             int K, int NB, int ldc,
             const float* __restrict__ rc, const float* __restrict__ rs)
{
  extern __shared__ char lds[];
  const int tid = threadIdx.x;
  const int l = tid & 63, w = tid >> 6;
  const int lr = l & 15, lg = l >> 4;
  const int wm = w >> 2, wn = w & 3;

  // XCD-bijective swizzle (m204)
  const int nwg = (int)gridDim.x;
  const int orig = (int)blockIdx.x;
  const int qq = nwg >> 3, rr = nwg & 7;
  const int xcd = orig & 7, idx = orig >> 3;
  const int wg = (xcd < rr ? xcd * (qq + 1) : rr * (qq + 1) + (xcd - rr) * qq) + idx;
  const int bm = wg / NB, bn = wg % NB;

  const size_t abase = (size_t)bm * 256 * (size_t)K;
  const size_t bbase = (size_t)bn * 256 * (size_t)K;

  float4v acc[8][4];
  const float4v fz = {0.f, 0.f, 0.f, 0.f};
#pragma unroll
  for (int i = 0; i < 8; ++i)
#pragma unroll
    for (int j = 0; j < 4; ++j) acc[i][j] = fz;

  const int nk = K >> 6;

  // prologue: tile0 -> buf0, then preload quarter-0 fragments
  ISSUE_HALF(1, 0, 0, 0)
  ISSUE_HALF(1, 1, 0, 0)
  ISSUE_HALF(0, 0, 0, 0)
  ISSUE_HALF(0, 1, 0, 0)
  asm volatile("s_waitcnt vmcnt(0)" ::: "memory");
  __builtin_amdgcn_s_barrier();

  short8v aC[4], aN[4], bC[4], bN[4];
  RD_A(aC[0], 0, 0, 0) RD_A(aC[1], 1, 0, 0) RD_A(aC[2], 2, 0, 0) RD_A(aC[3], 3, 0, 0)
  RD_B(bC[0], 0, 0, 0) RD_B(bC[1], 1, 0, 0) RD_B(bC[2], 2, 0, 0) RD_B(bC[3], 3, 0, 0)

  for (int t = 0; t < nk; ++t) {
    const int c = t & 1;

    // issue ALL of tile t+1 into the dead buffer at tile start (max distance)
    if (t + 1 < nk) {
      ISSUE_HALF(1, 0, t + 1, c ^ 1)
      ISSUE_HALF(1, 1, t + 1, c ^ 1)
      ISSUE_HALF(0, 0, t + 1, c ^ 1)
      ISSUE_HALF(0, 1, t + 1, c ^ 1)
    }

    // ---- pipelined quarters: read q+1 regs, then MFMA q (reads drain under MFMA)
    RD_A(aN[0], 4, 0, c) RD_A(aN[1], 5, 0, c) RD_A(aN[2], 6, 0, c) RD_A(aN[3], 7, 0, c)
    MFMA16(0, aC, bC)                               // q0: mi0-3, kk0

    RD_A(aC[0], 0, 1, c) RD_A(aC[1], 1, 1, c) RD_A(aC[2], 2, 1, c) RD_A(aC[3], 3, 1, c)
    RD_B(bN[0], 0, 1, c) RD_B(bN[1], 1, 1, c) RD_B(bN[2], 2, 1, c) RD_B(bN[3], 3, 1, c)
    MFMA16(4, aN, bC)                               // q1: mi4-7, kk0

    RD_A(aN[0], 4, 1, c) RD_A(aN[1], 5, 1, c) RD_A(aN[2], 6, 1, c) RD_A(aN[3], 7, 1, c)
    MFMA16(0, aC, bN)                               // q2: mi0-3, kk1

    // tile boundary: our ds_reads of buf c done (so t+1's DMA can't corrupt),
    // t+1's staging landed (issued one full tile ago), all waves synced.
    asm volatile("s_waitcnt lgkmcnt(0)" ::: "memory");
    __builtin_amdgcn_sched_barrier(0);
    asm volatile("s_waitcnt vmcnt(0)" ::: "memory");
    __builtin_amdgcn_s_barrier();

    MFMA16(4, aN, bN)                               // q3: mi4-7, kk1

    if (t + 1 < nk) {
      RD_A(aC[0], 0, 0, c ^ 1) RD_A(aC[1], 1, 0, c ^ 1) RD_A(aC[2], 2, 0, c ^ 1) RD_A(aC[3], 3, 0, c ^ 1)
      RD_B(bC[0], 0, 0, c ^ 1) RD_B(bC[1], 1, 0, c ^ 1) RD_B(bC[2], 2, 0, c ^ 1) RD_B(bC[3], 3, 0, c ^ 1)
    }
  }

  // ---- epilogue
  const int row0 = bm * 256 + wm * 128;
  const int col0 = bn * 256 + wn * 64;
  if (MODE == 3 && bn >= 16) {
    // V projection -> vt[bh][d][t] (transposed, ushort4 packed)
#pragma unroll
    for (int mi = 0; mi < 8; ++mi)
#pragma unroll
      for (int ni = 0; ni < 4; ++ni) {
        int vcol = col0 - 4096 + ni * 16 + lr;   // 0..2047 -> h,d
        int hh = vcol >> 7, dd = vcol & 127;
        int row = row0 + mi * 16 + lg * 4;
        int bb = row >> 11, t0 = row & 2047;
        ushort4 o4;
        o4.x = f2bf(acc[mi][ni][0]); o4.y = f2bf(acc[mi][ni][1]);
        o4.z = f2bf(acc[mi][ni][2]); o4.w = f2bf(acc[mi][ni][3]);
        *reinterpret_cast<ushort4*>(vtp + (((size_t)(bb * 16 + hh)) << 18) + (((size_t)dd) << 11) + t0) = o4;
      }
  } else if (MODE == 3) {
    // Q|K projection + fused RoPE: pair (2i,2i+1) in adjacent lanes of C-frag.
    const float sgn = (lr & 1) ? 1.0f : -1.0f;
#pragma unroll
    for (int mi = 0; mi < 8; ++mi)
#pragma unroll
      for (int ni = 0; ni < 4; ++ni) {
        int col = col0 + ni * 16 + lr;
        int ii = (col & 127) >> 1;
#pragma unroll
        for (int r2 = 0; r2 < 4; ++r2) {
          int row = row0 + mi * 16 + lg * 4 + r2;
          int tt = row & 2047;
          float v = acc[mi][ni][r2];
          float vp = __shfl_xor(v, 1);
          float cs = rc[tt * 64 + ii];
          float sn = rs[tt * 64 + ii];
          float o = v * cs + sgn * vp * sn;
          ((unsigned short*)Cout)[(size_t)row * ldc + col] = f2bf(o);
        }
      }
  } else {
#pragma unroll
    for (int mi = 0; mi < 8; ++mi)
#pragma unroll
      for (int ni = 0; ni < 4; ++ni)
#pragma unroll
        for (int r2 = 0; r2 < 4; ++r2) {
          int row = row0 + mi * 16 + lg * 4 + r2;
          int col = col0 + ni * 16 + lr;
          ((float*)Cout)[(size_t)row * ldc + col] = acc[mi][ni][r2];
        }
  }
}

// ---------------- causal flash attention (round-14 form: swapped QK^T, 32x32) ----
// 512 blocks x 256 threads; wg = (bh>>3)*64 + bx*8 + (bh&7): all 8 bx-blocks of a
// head land on ONE XCD -> K/V read once from HBM, 7x from L2. Each block runs
// q-tiles (15-bx, bx) sequentially = exactly 34 kv-stages (perfect balance).
// Round-16/17 lesson: merging both q-tiles into one 512-thread block serializes
// light waves behind heavy waves' barriers -> slower. Independent blocks win.
__global__ __launch_bounds__(256, 2)
void attn_kernel(const unsigned short* __restrict__ qk,
                 const unsigned short* __restrict__ vt,
                 unsigned short* __restrict__ out)
{
  __shared__ unsigned short Kl[2][64 * 128];
  __shared__ unsigned short Vl[2][128 * 64];

  const int wg = (int)blockIdx.x;
  const int bh = ((wg >> 6) << 3) | (wg & 7);
  const int bx = (wg >> 3) & 7;
  const int b = bh >> 4, h = bh & 15;
  const int tid = threadIdx.x, w = tid >> 6, l = tid & 63;
  const int q32 = l & 31, hi = l >> 5;
  const size_t rowbase = (size_t)b * T_;
  const unsigned short* kbase = qk + rowbase * LDQK + 2048 + h * HD_;
  const unsigned short* vbase = vt + (size_t)bh * (HD_ * (size_t)T_);
  const float SC = 0.12754089f;  // log2e / sqrt(128)
  const float16v z16 = {0.f,0.f,0.f,0.f,0.f,0.f,0.f,0.f,0.f,0.f,0.f,0.f,0.f,0.f,0.f,0.f};

#define STAGE(kv0_, bi_)                                                          \
  {                                                                               \
    _Pragma("unroll")                                                             \
    for (int i_ = 0; i_ < 4; ++i_) {                                              \
      int fo = (i_ * 256 + tid) * 16;                                             \
      int row = fo >> 8;                                                          \
      int cb = (fo & 255) ^ ((row & 15) << 4);                                    \
      GLDS16(kbase + (size_t)((kv0_) + row) * LDQK + (cb >> 1), (char*)Kl[bi_] + fo); \
    }                                                                             \
    _Pragma("unroll")                                                             \
    for (int i_ = 0; i_ < 4; ++i_) {                                              \
      int fo = (i_ * 256 + tid) * 16;                                             \
      int r6 = (fo >> 8) & 63;                                                    \
      int s_ = (fo >> 7) & 1;                                                     \
      int dd = r6 | ((s_ ^ ((r6 >> 3) & 1)) << 6);                                \
      int k16 = ((fo >> 4) & 7) ^ (dd & 7);                                       \
      GLDS16(vbase + (size_t)dd * T_ + (kv0_) + k16 * 8, (char*)Vl[bi_] + fo);    \
    }                                                                             \
  }

  for (int sel = 0; sel < 2; ++sel) {
    const int qt = sel ? bx : (15 - bx);
    const int q0w = qt * 128 + w * 32;
    const int qg = q0w + q32;

    // Q fragments (B-operand: col q=l&31, k=kf*16+hi*8+e), pre-scaled
    short8v qf[8];
#pragma unroll
    for (int kf = 0; kf < 8; ++kf) {
      short8v t = *reinterpret_cast<const short8v*>(
          qk + (rowbase + q0w + q32) * (size_t)LDQK + h * HD_ + kf * 16 + hi * 8);
      short8v r;
#pragma unroll
      for (int e = 0; e < 8; ++e) r[e] = (short)f2bf(bf2f((unsigned short)t[e]) * SC);
      qf[kf] = r;
    }

    float16v o[4];
#pragma unroll
    for (int db = 0; db < 4; ++db) o[db] = z16;
    float m_run = -1e30f, lsum = 0.f;

    const int nkv = 2 * (qt + 1);

    STAGE(0, 0);
    __syncthreads();

    for (int tile = 0; tile < nkv; ++tile) {
      const int kv0 = tile * 64;
      const int bi = tile & 1;
      if (tile + 1 < nkv) STAGE((tile + 1) * 64, bi ^ 1);

      if (kv0 <= q0w + 31) {
        // ---- S^T = K Q^T : D[key][q], two 32-key blocks
        float16v stv[2];
        stv[0] = z16; stv[1] = z16;
        __builtin_amdgcn_s_setprio(1);
#pragma unroll
        for (int kb = 0; kb < 2; ++kb) {
          int key = kb * 32 + q32;
          int swz = (key & 15) << 4;
          int rbase = key * 256;
#pragma unroll
          for (int kf = 0; kf < 8; ++kf) {
            short8v ak = *reinterpret_cast<const short8v*>(
                (char*)Kl[bi] + rbase + ((kf * 32 + hi * 16) ^ swz));
            stv[kb] = __builtin_amdgcn_mfma_f32_32x32x16_bf16(ak, qf[kf], stv[kb], 0, 0, 0);
          }
        }
        __builtin_amdgcn_s_setprio(0);
        // ---- causal mask (only partial tiles)
        if (kv0 + 63 > q0w) {
#pragma unroll
          for (int kb = 0; kb < 2; ++kb)
#pragma unroll
            for (int r = 0; r < 16; ++r) {
              int key = kv0 + kb * 32 + (r & 3) + 8 * ((r >> 2) & 3) + 4 * hi;
              if (key > qg) stv[kb][r] = -1e30f;
            }
        }
        // ---- row max (in-register tree + 1 cross-half shfl)
        float t16[16];
#pragma unroll
        for (int r = 0; r < 16; ++r) t16[r] = fmaxf(stv[0][r], stv[1][r]);
#pragma unroll
        for (int s = 8; s >= 1; s >>= 1)
#pragma unroll
          for (int r = 0; r < s; ++r) t16[r] = fmaxf(t16[r], t16[r + s]);
        float pm = fmaxf(t16[0], __shfl_xor(t16[0], 32));

        // ---- deferred rescale (T13, THR=8)
        if (!__all(pm <= m_run + 8.0f)) {
          float mn = fmaxf(m_run, pm);
          float fac = exp2f(m_run - mn);
          lsum *= fac;
          m_run = mn;
#pragma unroll
          for (int r = 0; r < 16; ++r) {
            int src = (r & 3) + 8 * ((r >> 2) & 3) + 4 * hi;
            float fr = __shfl(fac, src);
#pragma unroll
            for (int db = 0; db < 4; ++db) o[db][r] *= fr;
          }
        }
        // ---- P = exp2(s - m), row sum
        {
          float s16[16];
#pragma unroll
          for (int r = 0; r < 16; ++r) {
            float p0 = exp2f(stv[0][r] - m_run);
            float p1 = exp2f(stv[1][r] - m_run);
            stv[0][r] = p0; stv[1][r] = p1;
            s16[r] = p0 + p1;
          }
#pragma unroll
          for (int s = 8; s >= 1; s >>= 1)
#pragma unroll
            for (int r = 0; r < s; ++r) s16[r] += s16[r + s];
          lsum += s16[0] + __shfl_xor(s16[0], 32);
        }
        // ---- pack P to bf16 words (HW cvt_pk), exchange halves, build A-frags
        unsigned int pw0[8], pw1[8], xw0[8], xw1[8];
#pragma unroll
        for (int j = 0; j < 8; ++j) {
          pw0[j] = cvtpk_bf16(stv[0][2 * j], stv[0][2 * j + 1]);
          pw1[j] = cvtpk_bf16(stv[1][2 * j], stv[1][2 * j + 1]);
        }
#pragma unroll
        for (int j = 0; j < 8; ++j) {
          xw0[j] = __shfl_xor(pw0[j], 32);
          xw1[j] = __shfl_xor(pw1[j], 32);
        }
        union UW { unsigned int u[4]; short8v v; };
        short8v pb[4];
        {
          UW a0, a1, c0, c1;
          a0.u[0] = hi ? xw0[2] : pw0[0];  a0.u[1] = hi ? xw0[3] : pw0[1];
          a0.u[2] = hi ? pw0[2] : xw0[0];  a0.u[3] = hi ? pw0[3] : xw0[1];
          a1.u[0] = hi ? xw0[6] : pw0[4];  a1.u[1] = hi ? xw0[7] : pw0[5];
          a1.u[2] = hi ? pw0[6] : xw0[4];  a1.u[3] = hi ? pw0[7] : xw0[5];
          c0.u[0] = hi ? xw1[2] : pw1[0];  c0.u[1] = hi ? xw1[3] : pw1[1];
          c0.u[2] = hi ? pw1[2] : xw1[0];  c0.u[3] = hi ? pw1[3] : xw1[1];
          c1.u[0] = hi ? xw1[6] : pw1[4];  c1.u[1] = hi ? xw1[7] : pw1[5];
          c1.u[2] = hi ? pw1[6] : xw1[4];  c1.u[3] = hi ? pw1[7] : xw1[5];
          pb[0] = a0.v; pb[1] = a1.v; pb[2] = c0.v; pb[3] = c1.v;
        }
        // ---- O += P V  (B-operand = packed V^T rows from swizzled Vl)
        __builtin_amdgcn_s_setprio(1);
#pragma unroll
        for (int db = 0; db < 4; ++db) {
          int dd = db * 32 + q32;
          int rb2 = (dd & 63) * 256 + ((((dd >> 6) ^ ((dd >> 3) & 1)) & 1) << 7);
          int swz = (dd & 7) << 4;
#pragma unroll
          for (int kb16 = 0; kb16 < 4; ++kb16) {
            short8v bv = *reinterpret_cast<const short8v*>(
                (char*)Vl[bi] + rb2 + ((kb16 * 32 + hi * 16) ^ swz));
            o[db] = __builtin_amdgcn_mfma_f32_32x32x16_bf16(pb[kb16], bv, o[db], 0, 0, 0);
          }
        }
        __builtin_amdgcn_s_setprio(0);
      }
      __syncthreads();
    }

    // ---- epilogue: normalize and store bf16
    float linv = 1.0f / lsum;
#pragma unroll
    for (int r = 0; r < 16; ++r) {
      int src = (r & 3) + 8 * ((r >> 2) & 3) + 4 * hi;
      float lr_ = __shfl(linv, src);
      size_t rowoff = (rowbase + q0w + src) * (size_t)C_ + h * HD_ + q32;
#pragma unroll
      for (int db = 0; db < 4; ++db)
        out[rowoff + db * 32] = f2bf(o[db][r] * lr_);
    }
  }
#undef STAGE
}

// ---------------- launch ----------------
extern "C" void kernel_launch(void* const* d_in, const int* in_sizes, int n_in,
                              void* d_out, int out_size, void* d_ws, size_t ws_size,
                              hipStream_t stream) {
  (void)in_sizes; (void)n_in; (void)out_size; (void)ws_size;
  const float* x  = (const float*)d_in[0];
  const float* rc = (const float*)d_in[2];
  const float* rs = (const float*)d_in[3];
  const float* Wq = (const float*)d_in[4];
  const float* Wk = (const float*)d_in[5];
  const float* Wv = (const float*)d_in[6];
  const float* Wp = (const float*)d_in[7];
  float* outp = (float*)d_out;

  unsigned short* ws    = (unsigned short*)d_ws;
  unsigned short* x_bf  = ws;                       // 16,777,216
  unsigned short* wqkv  = x_bf + 16777216;          // 12,582,912 (Wq|Wk|Wv)
  unsigned short* wp_bf = wqkv + 12582912;          //  4,194,304 (contiguous after wqkv)
  unsigned short* qkbuf = wp_bf + 4194304;          // 33,554,432 (8192 x 4096)
  unsigned short* vtbuf = qkbuf + 33554432;         // 16,777,216 (64 x 128 x 2048)
  unsigned short* ao    = x_bf;                     // reuse after QKV GEMM

  // allow 128 KiB dynamic LDS (idempotent, capture-safe)
  hipFuncSetAttribute((const void*)gemm256<0>, hipFuncAttributeMaxDynamicSharedMemorySize, 131072);
  hipFuncSetAttribute((const void*)gemm256<3>, hipFuncAttributeMaxDynamicSharedMemorySize, 131072);

  // fused converts: x -> x_bf ; Wq|Wk|Wv|Wp -> wqkv..wp_bf (contiguous)
  cvt5_kernel<<<32768, 256, 0, stream>>>(x, Wq, Wk, Wv, Wp, x_bf, wqkv);

  // merged QKV projection: [8192,2048] x [6144,2048]^T, 768 blocks.
  // bn<16 -> q|k + fused RoPE into qkbuf; bn>=16 -> V transposed to vtbuf.
  gemm256<3><<<dim3(768), 512, 131072, stream>>>(x_bf, wqkv, qkbuf, vtbuf, 2048, 24, 4096, rc, rs);

  // causal attention (independent 256-thread blocks, XCD-colocated per head)
  attn_kernel<<<dim3(512), 256, 0, stream>>>(qkbuf, vtbuf, ao);

  // output projection -> f32
  gemm256<0><<<dim3(256), 512, 131072, stream>>>(ao, wp_bf, outp, nullptr, 2048, 8, 2048, nullptr, nullptr);
}